// Round 1
// baseline (175.349 us; speedup 1.0000x reference)
//
#include <hip/hip_runtime.h>

// Sinkhorn loss, mathematically collapsed:
//   For each of NP=4096 columns p (layout: element (t,p) at t*NP+p):
//     s_t = relu(v_t);  X_t = cumsum(s);  S = sum_t X_t = sum_i (NT-i)*s_i
//     loss_p = sum_t t * (X_t/Sx - Y_t/Sy)^2
//   output = sum_p loss_p
// (EMD collapses because both cumsums are non-decreasing -> identity argsort,
//  and weights w=arange give identical mass breakpoints for x and y.)

#define NT   4096
#define NP   4096
#define CH   64     // number of t-chunks
#define LCH  64     // chunk length; CH*LCH == NT
#define BLK  256

__global__ __launch_bounds__(BLK) void k1_chunk_sums(
    const float* __restrict__ x, const float* __restrict__ y,
    float* __restrict__ ax, float* __restrict__ ay,
    float* __restrict__ wx, float* __restrict__ wy) {
  const int p  = blockIdx.x * BLK + threadIdx.x;
  const int j  = blockIdx.y;
  const int t0 = j * LCH;
  const float* xp = x + (size_t)t0 * NP + p;
  const float* yp = y + (size_t)t0 * NP + p;
  float a_x = 0.f, a_y = 0.f, w_x = 0.f, w_y = 0.f;
#pragma unroll 8
  for (int i = 0; i < LCH; ++i) {
    float xv = fmaxf(xp[(size_t)i * NP], 0.f);
    float yv = fmaxf(yp[(size_t)i * NP], 0.f);
    const float wgt = (float)(NT - (t0 + i));
    a_x += xv;        a_y += yv;
    w_x += wgt * xv;  w_y += wgt * yv;
  }
  const int o = j * NP + p;
  ax[o] = a_x; ay[o] = a_y; wx[o] = w_x; wy[o] = w_y;
}

__global__ __launch_bounds__(BLK) void k2_scan(
    const float* __restrict__ ax, const float* __restrict__ ay,
    const float* __restrict__ wx, const float* __restrict__ wy,
    double* __restrict__ Ox, double* __restrict__ Oy,
    double* __restrict__ iSx, double* __restrict__ iSy) {
  const int p = blockIdx.x * BLK + threadIdx.x;
  double ox = 0.0, oy = 0.0, sx = 0.0, sy = 0.0;
  for (int j = 0; j < CH; ++j) {
    const int o = j * NP + p;
    Ox[o] = ox; Oy[o] = oy;
    ox += (double)ax[o]; oy += (double)ay[o];
    sx += (double)wx[o]; sy += (double)wy[o];
  }
  iSx[p] = 1.0 / sx;
  iSy[p] = 1.0 / sy;
}

__global__ __launch_bounds__(BLK) void k3_loss(
    const float* __restrict__ x, const float* __restrict__ y,
    const double* __restrict__ Ox, const double* __restrict__ Oy,
    const double* __restrict__ iSx, const double* __restrict__ iSy,
    double* __restrict__ part) {
  const int p  = blockIdx.x * BLK + threadIdx.x;
  const int j  = blockIdx.y;
  const int t0 = j * LCH;
  const float* xp = x + (size_t)t0 * NP + p;
  const float* yp = y + (size_t)t0 * NP + p;
  const int o = j * NP + p;
  double cx = Ox[o], cy = Oy[o];
  const double isx = iSx[p], isy = iSy[p];
  double acc = 0.0;
#pragma unroll 4
  for (int i = 0; i < LCH; ++i) {
    float xv = fmaxf(xp[(size_t)i * NP], 0.f);
    float yv = fmaxf(yp[(size_t)i * NP], 0.f);
    cx += (double)xv;
    cy += (double)yv;
    const double d = cx * isx - cy * isy;
    acc += (double)(t0 + i) * d * d;
  }
  __shared__ double red[BLK];
  red[threadIdx.x] = acc;
  __syncthreads();
  for (int s = BLK / 2; s > 0; s >>= 1) {
    if (threadIdx.x < s) red[threadIdx.x] += red[threadIdx.x + s];
    __syncthreads();
  }
  if (threadIdx.x == 0)
    part[blockIdx.y * gridDim.x + blockIdx.x] = red[0];
}

__global__ __launch_bounds__(1024) void k4_final(
    const double* __restrict__ part, float* __restrict__ out) {
  __shared__ double red[1024];
  red[threadIdx.x] = part[threadIdx.x];  // exactly 1024 partials
  __syncthreads();
  for (int s = 512; s > 0; s >>= 1) {
    if (threadIdx.x < s) red[threadIdx.x] += red[threadIdx.x + s];
    __syncthreads();
  }
  if (threadIdx.x == 0) out[0] = (float)red[0];
}

extern "C" void kernel_launch(void* const* d_in, const int* in_sizes, int n_in,
                              void* d_out, int out_size, void* d_ws, size_t ws_size,
                              hipStream_t stream) {
  const float* x = (const float*)d_in[0];
  const float* y = (const float*)d_in[1];
  float* out = (float*)d_out;

  const size_t CNP = (size_t)CH * NP;
  char* ws = (char*)d_ws;
  float*  ax   = (float*)ws;            ws += CNP * sizeof(float);
  float*  ay   = (float*)ws;            ws += CNP * sizeof(float);
  float*  wx   = (float*)ws;            ws += CNP * sizeof(float);
  float*  wy   = (float*)ws;            ws += CNP * sizeof(float);
  double* Ox   = (double*)ws;           ws += CNP * sizeof(double);
  double* Oy   = (double*)ws;           ws += CNP * sizeof(double);
  double* iSx  = (double*)ws;           ws += (size_t)NP * sizeof(double);
  double* iSy  = (double*)ws;           ws += (size_t)NP * sizeof(double);
  double* part = (double*)ws;           ws += (size_t)(NP / BLK) * CH * sizeof(double);

  dim3 g1(NP / BLK, CH);
  k1_chunk_sums<<<g1, BLK, 0, stream>>>(x, y, ax, ay, wx, wy);
  k2_scan<<<NP / BLK, BLK, 0, stream>>>(ax, ay, wx, wy, Ox, Oy, iSx, iSy);
  k3_loss<<<g1, BLK, 0, stream>>>(x, y, Ox, Oy, iSx, iSy, part);
  k4_final<<<1, 1024, 0, stream>>>(part, out);
}